// Round 1
// 209.336 us; speedup vs baseline: 1.6379x; 1.6379x over previous
//
#include <hip/hip_runtime.h>
#include <math.h>

// Problem constants (fixed by setup_inputs)
#define BATCH 32768
#define SS 16          // bands / sequence
#define DI 14          // input dim
#define BQ 256         // stored patterns
#define NC 7           // classes

#define NBLK 2048      // main-kernel grid (4 waves/block -> 8192 waves, 4 batches/wave)
#define TOTW (NBLK * 4)

// ws layout (unchanged):
//   kpack : double2[7][256]   (28672 B)  LN_st(lookup) packed as dim-pairs x pattern
//   Tf    : float[256*7]      ( 7168 B)  per-pattern class contribution table
//   zb    : double[7]         (   56 B)  bm[c]*sum(Wb) + bb
#define WS_KPACK_OFF 0
#define WS_TF_OFF    28672
#define WS_ZB_OFF    (28672 + 7168)

typedef float v2f __attribute__((ext_vector_type(2)));

// Monotone fp32->u32 order map, packed with (255-j) into a positive fp64 DENORMAL
// (bits < 2^40 => exponent field 0). Denormal doubles compare exactly like their
// u64 bit patterns (IEEE monotonicity; CDNA fp64 never flushes denormals), so a
// single v_max_f64 does "max value, tie -> lowest index".
__device__ __forceinline__ double pack_key(float v, int j) {
    unsigned u = __float_as_uint(v);
    u ^= ((unsigned)((int)u >> 31)) | 0x80000000u;
    const unsigned long long k =
        ((unsigned long long)u << 8) | (unsigned long long)(255 - j);
    return __longlong_as_double((long long)k);
}

__global__ __launch_bounds__(256) void precompute_kernel(
    const float* __restrict__ lookup,
    const float* __restrict__ g_st, const float* __restrict__ b_st,
    const float* __restrict__ g_pp, const float* __restrict__ b_pp,
    const float* __restrict__ Wv,  const float* __restrict__ Wo,
    const float* __restrict__ Wm,  const float* __restrict__ bm,
    const float* __restrict__ Wb,  const float* __restrict__ bb,
    double2* __restrict__ kpack, float* __restrict__ Tf, double* __restrict__ zb)
{
    __shared__ double G1s[256][7];   // (Wo.T @ Wm.T)  : [p][c]
    __shared__ double Gs[14][7];     // Wv.T @ G1      : [d][c]
    const int tid = threadIdx.x;

    // G1[p][c] = sum_o Wo[o,p] * Wm[c,o]
    {
        const int p = tid;
        for (int c = 0; c < NC; ++c) {
            double acc = 0.0;
            for (int o = 0; o < 28; ++o)
                acc += (double)Wo[o * 256 + p] * (double)Wm[c * 28 + o];
            G1s[p][c] = acc;
        }
    }
    __syncthreads();
    // G[d][c] = sum_p Wv[p,d] * G1[p][c]
    if (tid < DI * NC) {
        const int d = tid / NC, c = tid % NC;
        double acc = 0.0;
        for (int p = 0; p < 256; ++p)
            acc += (double)Wv[p * DI + d] * G1s[p][c];
        Gs[d][c] = acc;
    }
    __syncthreads();

    // Per stored pattern j: LayerNorm once (shared mu/var), emit k (fp64) and T row.
    {
        const int j = tid;
        double xr[DI];
        double sum = 0.0;
        for (int d = 0; d < DI; ++d) { xr[d] = (double)lookup[j * DI + d]; sum += xr[d]; }
        const double mu = sum * (1.0 / (double)DI);
        double vs = 0.0;
        for (int d = 0; d < DI; ++d) { const double t = xr[d] - mu; vs += t * t; }
        const double rs = 1.0 / sqrt(vs * (1.0 / (double)DI) + 1e-5);

        double kj[DI], vl[DI];
        for (int d = 0; d < DI; ++d) {
            const double nrm = (xr[d] - mu) * rs;
            kj[d] = nrm * (double)g_st[d] + (double)b_st[d];
            vl[d] = nrm * (double)g_pp[d] + (double)b_pp[d];
        }
        for (int d2 = 0; d2 < DI / 2; ++d2) {
            double2 kv; kv.x = kj[2 * d2]; kv.y = kj[2 * d2 + 1];
            kpack[d2 * 256 + j] = kv;
        }
        for (int c = 0; c < NC; ++c) {
            double acc = 0.0;
            for (int d = 0; d < DI; ++d) acc += vl[d] * Gs[d][c];
            Tf[j * NC + c] = (float)acc;
        }
    }
    if (tid < NC) {
        double wbsum = 0.0;
        for (int s = 0; s < SS; ++s) wbsum += (double)Wb[s];
        zb[tid] = (double)bm[tid] * wbsum + (double)bb[0];
    }
}

// One wave = one batch. 4 groups x 16 lanes; each lane holds 4 rows' q in regs and
// scans 16 patterns (j = jj*16 + l). fp32 scan with 2 disjoint in-lane trackers,
// group top-2 reduce via packed-key fmax, then fp64 rescore of the 2 candidates
// per row with arithmetic bit-identical to the previous (passing) fp64 kernel.
__global__ __launch_bounds__(256, 3) void hopfield_kernel(
    const float* __restrict__ x,
    const float* __restrict__ g_sp, const float* __restrict__ b_sp,
    const double2* __restrict__ kpack, const float* __restrict__ Tf,
    const double* __restrict__ zb, const float* __restrict__ Wb,
    float* __restrict__ out)
{
    __shared__ v2f    kfs[7 * 256];          // fp32 k, [d2][j]   14336 B
    __shared__ float  Ts[256 * NC];          //                    7168 B
    __shared__ double zbs[NC];
    __shared__ float  wbs[SS];
    __shared__ float  gsps[DI], bsps[DI];
    __shared__ v2f    qshf[4][SS * 7];       // per-wave fp32 LN'd q (896 B each)
    __shared__ int    jcand[4][SS][2];
    __shared__ int    jstarS[4][SS];
    __shared__ double zrowd[4][NC];

    const int tid  = threadIdx.x;
    const int lane = tid & 63;
    const int w    = tid >> 6;
    const int g    = lane >> 4;   // row-group 0..3
    const int l    = lane & 15;   // pattern sub-lane

    for (int i = tid; i < 7 * 256; i += 256) {
        const double2 kv = kpack[i];
        v2f f; f.x = (float)kv.x; f.y = (float)kv.y;
        kfs[i] = f;
    }
    for (int i = tid; i < 256 * NC; i += 256) Ts[i] = Tf[i];
    if (tid < NC) zbs[tid] = zb[tid];
    if (tid < SS) wbs[tid] = Wb[tid];
    if (tid < DI) { gsps[tid] = g_sp[tid]; bsps[tid] = b_sp[tid]; }
    __syncthreads();

    const int gw = blockIdx.x * 4 + w;

    for (int b = gw; b < BATCH; b += TOTW) {
        // ---- fp32 LN of the 16 state rows (lanes 0..15), into per-wave LDS ----
        if (lane < SS) {
            const int s = lane;
            const float* xr = x + ((size_t)b * SS + s) * DI;
            float xv[DI]; float sum = 0.f;
            #pragma unroll
            for (int d = 0; d < DI; ++d) { xv[d] = xr[d]; sum += xv[d]; }
            const float mu = sum * (1.0f / (float)DI);
            float vs = 0.f;
            #pragma unroll
            for (int d = 0; d < DI; ++d) { const float t = xv[d] - mu; vs += t * t; }
            const float rs = 1.0f / sqrtf(vs * (1.0f / (float)DI) + 1e-5f);
            #pragma unroll
            for (int d2 = 0; d2 < 7; ++d2) {
                v2f q;
                q.x = (xv[2 * d2]     - mu) * rs * gsps[2 * d2]     + bsps[2 * d2];
                q.y = (xv[2 * d2 + 1] - mu) * rs * gsps[2 * d2 + 1] + bsps[2 * d2 + 1];
                qshf[w][s * 7 + d2] = q;
            }
        }
        __builtin_amdgcn_wave_barrier();   // DS pipe is in-order per wave

        // ---- fp32 scan: 4 rows in regs per lane, 16 patterns per lane ----
        v2f q[4][7];
        const int r0 = g * 4;
        #pragma unroll
        for (int r = 0; r < 4; ++r)
            #pragma unroll
            for (int d2 = 0; d2 < 7; ++d2)
                q[r][d2] = qshf[w][(r0 + r) * 7 + d2];

        float t0v[4], t1v[4]; int t0j[4], t1j[4];
        #pragma unroll
        for (int r = 0; r < 4; ++r) {
            t0v[r] = -INFINITY; t1v[r] = -INFINITY; t0j[r] = 0; t1j[r] = 1;
        }

        #pragma unroll
        for (int jj = 0; jj < 16; ++jj) {
            const int j = jj * 16 + l;
            v2f kv[7];
            #pragma unroll
            for (int d2 = 0; d2 < 7; ++d2) kv[d2] = kfs[d2 * 256 + j];
            v2f acc[4];
            #pragma unroll
            for (int r = 0; r < 4; ++r) {
                acc[r] = q[r][0] * kv[0];
                #pragma unroll
                for (int d2 = 1; d2 < 7; ++d2) acc[r] += q[r][d2] * kv[d2];
            }
            #pragma unroll
            for (int r = 0; r < 4; ++r) {
                const float s = acc[r].x + acc[r].y;
                if (jj & 1) {
                    const bool c = s > t1v[r];
                    t1v[r] = c ? s : t1v[r]; t1j[r] = c ? jj : t1j[r];
                } else {
                    const bool c = s > t0v[r];
                    t0v[r] = c ? s : t0v[r]; t0j[r] = c ? jj : t0j[r];
                }
            }
        }

        // ---- top-2 reduce within each 16-lane group (packed fp64-denormal keys) ----
        double kh[4], kl[4];
        #pragma unroll
        for (int r = 0; r < 4; ++r) {
            const double k0 = pack_key(t0v[r], t0j[r] * 16 + l);
            const double k1 = pack_key(t1v[r], t1j[r] * 16 + l);
            kh[r] = fmax(k0, k1);
            kl[r] = fmin(k0, k1);
        }
        #pragma unroll
        for (int off = 8; off > 0; off >>= 1) {
            #pragma unroll
            for (int r = 0; r < 4; ++r) {
                const double oh = __shfl_down(kh[r], (unsigned)off, 16);
                const double ol = __shfl_down(kl[r], (unsigned)off, 16);
                const double nh = fmax(kh[r], oh);
                const double nl = fmax(fmin(kh[r], oh), fmax(kl[r], ol));
                kh[r] = nh; kl[r] = nl;
            }
        }
        if (l == 0) {
            #pragma unroll
            for (int r = 0; r < 4; ++r) {
                jcand[w][r0 + r][0] = 255 - (int)(__double_as_longlong(kh[r]) & 0xFF);
                jcand[w][r0 + r][1] = 255 - (int)(__double_as_longlong(kl[r]) & 0xFF);
            }
        }
        __builtin_amdgcn_wave_barrier();

        // ---- fp64 rescore of 2 candidates/row (lanes 0..31), bit-identical LN+dot ----
        if (lane < 2 * SS) {
            const int row = lane >> 1;
            const int j   = jcand[w][row][lane & 1];
            const float* xr = x + ((size_t)b * SS + row) * DI;
            double xv[DI]; double sum = 0.0;
            #pragma unroll
            for (int d = 0; d < DI; ++d) { xv[d] = (double)xr[d]; sum += xv[d]; }
            const double mu = sum * (1.0 / (double)DI);
            double vs = 0.0;
            #pragma unroll
            for (int d = 0; d < DI; ++d) { const double t = xv[d] - mu; vs += t * t; }
            const double rs = 1.0 / sqrt(vs * (1.0 / (double)DI) + 1e-5);
            double qd[DI];
            #pragma unroll
            for (int d = 0; d < DI; ++d)
                qd[d] = (xv[d] - mu) * rs * (double)gsps[d] + (double)bsps[d];
            double a = 0.0;
            #pragma unroll
            for (int d2 = 0; d2 < 7; ++d2) {
                const double2 kv = kpack[d2 * 256 + j];
                a += qd[2 * d2] * kv.x;
                a += qd[2 * d2 + 1] * kv.y;
            }
            const double oa = __shfl_xor(a, 1);
            const int    oj = __shfl_xor(j, 1);
            const int jwin = (a > oa || (a == oa && j < oj)) ? j : oj;
            if ((lane & 1) == 0) jstarS[w][row] = jwin;
        }
        __builtin_amdgcn_wave_barrier();

        // ---- head: z fp64 (matches old kernel), softmax fp32 ----
        if (lane < NC) {
            double z = zbs[lane];
            #pragma unroll
            for (int s = 0; s < SS; ++s)
                z += (double)wbs[s] * (double)Ts[jstarS[w][s] * NC + lane];
            zrowd[w][lane] = z;
        }
        __builtin_amdgcn_wave_barrier();
        if (lane < NC) {
            double m = zrowd[w][0];
            #pragma unroll
            for (int c = 1; c < NC; ++c) m = fmax(m, zrowd[w][c]);
            float den = 0.f;
            #pragma unroll
            for (int c = 0; c < NC; ++c) den += __expf((float)(zrowd[w][c] - m));
            const float num = __expf((float)(zrowd[w][lane] - m));
            out[(size_t)b * NC + lane] = num / den;
        }
        __builtin_amdgcn_wave_barrier();
    }
}

extern "C" void kernel_launch(void* const* d_in, const int* in_sizes, int n_in,
                              void* d_out, int out_size, void* d_ws, size_t ws_size,
                              hipStream_t stream) {
    const float* x      = (const float*)d_in[0];
    const float* lookup = (const float*)d_in[1];
    const float* g_st   = (const float*)d_in[2];
    const float* b_st   = (const float*)d_in[3];
    const float* g_sp   = (const float*)d_in[4];
    const float* b_sp   = (const float*)d_in[5];
    const float* g_pp   = (const float*)d_in[6];
    const float* b_pp   = (const float*)d_in[7];
    const float* Wv     = (const float*)d_in[8];
    const float* Wo     = (const float*)d_in[9];
    const float* Wm     = (const float*)d_in[10];
    const float* bm     = (const float*)d_in[11];
    const float* Wb     = (const float*)d_in[12];
    const float* bb     = (const float*)d_in[13];

    double2* kpack = (double2*)((char*)d_ws + WS_KPACK_OFF);
    float*   Tf    = (float*)((char*)d_ws + WS_TF_OFF);
    double*  zb    = (double*)((char*)d_ws + WS_ZB_OFF);

    precompute_kernel<<<1, 256, 0, stream>>>(lookup, g_st, b_st, g_pp, b_pp,
                                             Wv, Wo, Wm, bm, Wb, bb,
                                             kpack, Tf, zb);
    hopfield_kernel<<<NBLK, 256, 0, stream>>>(x, g_sp, b_sp, kpack, Tf, zb, Wb,
                                              (float*)d_out);
}

// Round 2
// 161.688 us; speedup vs baseline: 2.1206x; 1.2947x over previous
//
#include <hip/hip_runtime.h>
#include <math.h>

// Problem constants (fixed by setup_inputs)
#define BATCH 32768
#define SS 16          // bands / sequence
#define DI 14          // input dim
#define BQ 256         // stored patterns
#define NC 7           // classes
#define NBLK 2048      // 4 waves/block -> 8192 waves, 4 contiguous batches/wave

// ws layout:
//   mpack : double2[7][256]  (28672 B) m-tilde = g_sp*k - (S/14), packed dim-pairs x pattern
//   Tf    : float[256*7]     ( 7168 B) per-pattern class contribution table
//   zb    : double[7]        (   56 B) bm[c]*sum(Wb) + bb
//   cvec  : double[256]      ( 2048 B) c_j = b_sp . k_j   (all 0 for these inputs)
//   hc    : int              (    4 B) any(b_sp != 0)
#define WS_MPACK_OFF 0
#define WS_TF_OFF    28672
#define WS_ZB_OFF    35840
#define WS_CV_OFF    35896
#define WS_HC_OFF    37944

typedef float  f32x4 __attribute__((ext_vector_type(4)));
typedef short  s16x8 __attribute__((ext_vector_type(8)));
typedef float  v2f   __attribute__((ext_vector_type(2)));

__device__ __forceinline__ unsigned short bf16_rne(float f) {
    unsigned u = __float_as_uint(f);
    unsigned r = u + 0x7FFFu + ((u >> 16) & 1u);
    return (unsigned short)(r >> 16);
}
__device__ __forceinline__ float bf16_to_f32(unsigned short h) {
    return __uint_as_float(((unsigned)h) << 16);
}

// Monotone fp32->u32 order map packed with (255-j) into a positive fp64 DENORMAL
// (bits < 2^40). Denormal doubles compare like their u64 bit patterns, so a
// single v_max_f64 does "max value, tie -> lowest index".  (proven in R1)
__device__ __forceinline__ double pack_key(float v, int j) {
    unsigned u = __float_as_uint(v);
    u ^= ((unsigned)((int)u >> 31)) | 0x80000000u;
    const unsigned long long k =
        ((unsigned long long)u << 8) | (unsigned long long)(255 - j);
    return __longlong_as_double((long long)k);
}

__global__ __launch_bounds__(256) void precompute_kernel(
    const float* __restrict__ lookup,
    const float* __restrict__ g_st, const float* __restrict__ b_st,
    const float* __restrict__ g_pp, const float* __restrict__ b_pp,
    const float* __restrict__ g_sp, const float* __restrict__ b_sp,
    const float* __restrict__ Wv,  const float* __restrict__ Wo,
    const float* __restrict__ Wm,  const float* __restrict__ bm,
    const float* __restrict__ Wb,  const float* __restrict__ bb,
    double2* __restrict__ mpack, float* __restrict__ Tf, double* __restrict__ zb,
    double* __restrict__ cvec, int* __restrict__ hc)
{
    __shared__ double G1s[256][7];   // (Wo.T @ Wm.T)  : [p][c]
    __shared__ double Gs[14][7];     // Wv.T @ G1      : [d][c]
    const int tid = threadIdx.x;

    // G1[p][c] = sum_o Wo[o,p] * Wm[c,o]
    {
        const int p = tid;
        for (int c = 0; c < NC; ++c) {
            double acc = 0.0;
            for (int o = 0; o < 28; ++o)
                acc += (double)Wo[o * 256 + p] * (double)Wm[c * 28 + o];
            G1s[p][c] = acc;
        }
    }
    __syncthreads();
    // G[d][c] = sum_p Wv[p,d] * G1[p][c]
    if (tid < DI * NC) {
        const int d = tid / NC, c = tid % NC;
        double acc = 0.0;
        for (int p = 0; p < 256; ++p)
            acc += (double)Wv[p * DI + d] * G1s[p][c];
        Gs[d][c] = acc;
    }
    __syncthreads();

    // Per stored pattern j: LayerNorm once (fp64), emit m-tilde, c_j, T row.
    {
        const int j = tid;
        double xr[DI];
        double sum = 0.0;
        for (int d = 0; d < DI; ++d) { xr[d] = (double)lookup[j * DI + d]; sum += xr[d]; }
        const double mu = sum * (1.0 / (double)DI);
        double vs = 0.0;
        for (int d = 0; d < DI; ++d) { const double t = xr[d] - mu; vs += t * t; }
        const double rs = 1.0 / sqrt(vs * (1.0 / (double)DI) + 1e-5);

        double kj[DI], vl[DI];
        for (int d = 0; d < DI; ++d) {
            const double nrm = (xr[d] - mu) * rs;
            kj[d] = nrm * (double)g_st[d] + (double)b_st[d];
            vl[d] = nrm * (double)g_pp[d] + (double)b_pp[d];
        }
        // m_j = g_sp .* k_j ; m~_j = m_j - (sum m_j)/14 ; c_j = b_sp . k_j
        double mv[DI], S = 0.0, cj = 0.0;
        for (int d = 0; d < DI; ++d) {
            mv[d] = kj[d] * (double)g_sp[d];
            S += mv[d];
            cj += (double)b_sp[d] * kj[d];
        }
        const double Sm = S * (1.0 / (double)DI);
        for (int d2 = 0; d2 < DI / 2; ++d2) {
            double2 p; p.x = mv[2 * d2] - Sm; p.y = mv[2 * d2 + 1] - Sm;
            mpack[d2 * 256 + j] = p;
        }
        cvec[j] = cj;

        for (int c = 0; c < NC; ++c) {
            double acc = 0.0;
            for (int d = 0; d < DI; ++d) acc += vl[d] * Gs[d][c];
            Tf[j * NC + c] = (float)acc;
        }
    }
    if (tid < NC) {
        double wbsum = 0.0;
        for (int s = 0; s < SS; ++s) wbsum += (double)Wb[s];
        zb[tid] = (double)bm[tid] * wbsum + (double)bb[0];
    }
    if (tid == 0) {
        int f = 0;
        for (int d = 0; d < DI; ++d) f |= (b_sp[d] != 0.0f) ? 1 : 0;
        *hc = f;
    }
}

// One wave = 4 contiguous batches (single superstep, no loop).
// Scan per batch: A = raw x rows (16x32, K padded), B tiles = m~ patterns,
// 3-term bf16-split MFMA (A_h B_h + A_h B_l + A_l B_h) ~ fp32-accurate scores.
// C/D layout: col = lane&15 (pattern sub-idx), row = (lane>>4)*4+reg -> feeds
// the proven parity-tracker + fp64-denormal-key top-2 reduce unchanged.
// fp64 rescore of 2 candidates/row = bare 14-dim dot x . m~_j (no LN needed).
__global__ __launch_bounds__(256, 4) void hopfield_kernel(
    const float* __restrict__ x,
    const double2* __restrict__ mpack, const double* __restrict__ cvec,
    const int* __restrict__ hcp,
    const float* __restrict__ Tf, const double* __restrict__ zb,
    const float* __restrict__ Wb, float* __restrict__ out)
{
    __shared__ s16x8  bhiS[16 * 32];          // B hi frags  [tile][lane<32]  8 KiB
    __shared__ s16x8  bloS[16 * 32];          // B lo frags                   8 KiB
    __shared__ float  Ts[256 * NC];           //                              7 KiB
    __shared__ double zbs[NC];
    __shared__ float  wbs[SS];
    __shared__ int    jcandS[4][4][SS][2];    // [wave][bi][row][cand]
    __shared__ int    jstarS[4][4][SS];
    __shared__ double zrowd[4][4][NC];
    __shared__ float  irsS[4][4][SS];         // general path only (hc != 0)

    const int tid  = threadIdx.x;
    const int lane = tid & 63;
    const int w    = tid >> 6;
    const int g    = lane >> 4;   // A k-slab / C row-group
    const int l    = lane & 15;   // A row (band) / C col (pattern sub-idx)
    const int hc   = *hcp;

    // ---- build B fragments (hi/lo bf16 splits of fp32(m~)) in LDS ----
    {
        const int j = tid;
        float mf[16];
        #pragma unroll
        for (int d2 = 0; d2 < 7; ++d2) {
            const double2 mv = mpack[d2 * 256 + j];
            mf[2 * d2] = (float)mv.x; mf[2 * d2 + 1] = (float)mv.y;
        }
        mf[14] = (float)cvec[j];   // pairs with A dim14 = irs (general path; 0 here)
        mf[15] = 0.f;
        #pragma unroll
        for (int ks = 0; ks < 2; ++ks) {
            s16x8 h8, l8;
            #pragma unroll
            for (int i = 0; i < 8; ++i) {
                const float f = mf[8 * ks + i];
                const unsigned short h = bf16_rne(f);
                const float r = f - bf16_to_f32(h);     // exact (Sterbenz)
                h8[i] = (short)h;
                l8[i] = (short)bf16_rne(r);
            }
            bhiS[(j >> 4) * 32 + ks * 16 + (j & 15)] = h8;
            bloS[(j >> 4) * 32 + ks * 16 + (j & 15)] = l8;
        }
    }
    for (int i = tid; i < 256 * NC; i += 256) Ts[i] = Tf[i];
    if (tid < NC) zbs[tid] = zb[tid];
    if (tid < SS) wbs[tid] = Wb[tid];
    __syncthreads();

    const int gw = blockIdx.x * 4 + w;               // 0..8191
    const float* xw = x + (size_t)gw * 4 * SS * DI;  // this wave's 4 batches

    // ---- phase 0 (general path only): fp32 inv-std per (bi,row) ----
    if (hc) {
        const int bi = lane >> 4, s = lane & 15;
        const float* xr = xw + (bi * SS + s) * DI;
        float xv[DI]; float sum = 0.f;
        #pragma unroll
        for (int d = 0; d < DI; ++d) { xv[d] = xr[d]; sum += xv[d]; }
        const float mu = sum * (1.0f / (float)DI);
        float vs = 0.f;
        #pragma unroll
        for (int d = 0; d < DI; ++d) { const float t = xv[d] - mu; vs += t * t; }
        irsS[w][bi][s] = 1.0f / sqrtf(vs * (1.0f / (float)DI) + 1e-5f);
        __builtin_amdgcn_wave_barrier();
    }

    // ---- scan: 4 batches, 16 MFMA tiles each ----
    for (int bi = 0; bi < 4; ++bi) {
        s16x8 ah = {0,0,0,0,0,0,0,0}, al = {0,0,0,0,0,0,0,0};
        if (lane < 32) {   // k-slabs 0,1 hold real dims; slabs 2,3 stay zero
            const float* xr = xw + (bi * SS + l) * DI;
            float xv[8];
            if (g == 0) {
                #pragma unroll
                for (int i = 0; i < 4; ++i) {
                    const v2f p = *(const v2f*)(xr + 2 * i);
                    xv[2 * i] = p.x; xv[2 * i + 1] = p.y;
                }
            } else {
                #pragma unroll
                for (int i = 0; i < 3; ++i) {
                    const v2f p = *(const v2f*)(xr + 8 + 2 * i);
                    xv[2 * i] = p.x; xv[2 * i + 1] = p.y;
                }
                xv[6] = hc ? irsS[w][bi][l] : 0.f;   // dim14: irs (general path)
                xv[7] = 0.f;
            }
            #pragma unroll
            for (int i = 0; i < 8; ++i) {
                const unsigned short h = bf16_rne(xv[i]);
                const float r = xv[i] - bf16_to_f32(h);
                ah[i] = (short)h;
                al[i] = (short)bf16_rne(r);
            }
        }

        float t0v[4], t1v[4]; int t0j[4], t1j[4];
        #pragma unroll
        for (int r = 0; r < 4; ++r) {
            t0v[r] = -INFINITY; t1v[r] = -INFINITY; t0j[r] = 0; t1j[r] = 1;
        }
        const f32x4 z4 = {0.f, 0.f, 0.f, 0.f};

        #pragma unroll
        for (int t = 0; t < 16; ++t) {
            s16x8 bh = {0,0,0,0,0,0,0,0}, bl = {0,0,0,0,0,0,0,0};
            if (lane < 32) { bh = bhiS[t * 32 + lane]; bl = bloS[t * 32 + lane]; }
            f32x4 acc = __builtin_amdgcn_mfma_f32_16x16x32_bf16(al, bh, z4, 0, 0, 0);
            acc = __builtin_amdgcn_mfma_f32_16x16x32_bf16(ah, bl, acc, 0, 0, 0);
            acc = __builtin_amdgcn_mfma_f32_16x16x32_bf16(ah, bh, acc, 0, 0, 0);
            #pragma unroll
            for (int r = 0; r < 4; ++r) {
                const float s = acc[r];
                if (t & 1) {
                    const bool c = s > t1v[r];
                    t1v[r] = c ? s : t1v[r]; t1j[r] = c ? t : t1j[r];
                } else {
                    const bool c = s > t0v[r];
                    t0v[r] = c ? s : t0v[r]; t0j[r] = c ? t : t0j[r];
                }
            }
        }

        // top-2 reduce within each 16-lane group (packed fp64-denormal keys)
        double kh[4], kl[4];
        #pragma unroll
        for (int r = 0; r < 4; ++r) {
            const double k0 = pack_key(t0v[r], t0j[r] * 16 + l);
            const double k1 = pack_key(t1v[r], t1j[r] * 16 + l);
            kh[r] = fmax(k0, k1);
            kl[r] = fmin(k0, k1);
        }
        #pragma unroll
        for (int off = 8; off > 0; off >>= 1) {
            #pragma unroll
            for (int r = 0; r < 4; ++r) {
                const double oh = __shfl_down(kh[r], (unsigned)off, 16);
                const double ol = __shfl_down(kl[r], (unsigned)off, 16);
                const double nh = fmax(kh[r], oh);
                const double nl = fmax(fmin(kh[r], oh), fmax(kl[r], ol));
                kh[r] = nh; kl[r] = nl;
            }
        }
        if (l == 0) {
            #pragma unroll
            for (int r = 0; r < 4; ++r) {
                jcandS[w][bi][g * 4 + r][0] = 255 - (int)(__double_as_longlong(kh[r]) & 0xFF);
                jcandS[w][bi][g * 4 + r][1] = 255 - (int)(__double_as_longlong(kl[r]) & 0xFF);
            }
        }
    }
    __builtin_amdgcn_wave_barrier();

    // ---- fp64 rescore: 128 tasks (4 bi x 16 rows x 2 cands) on 64 lanes x 2 ----
    #pragma unroll
    for (int u = 0; u < 2; ++u) {
        const int task = u * 64 + lane;
        const int bi = task >> 5, row = (task >> 1) & 15, ci = task & 1;
        const int j = jcandS[w][bi][row][ci];
        const float* xr = xw + (bi * SS + row) * DI;
        double a = 0.0;
        #pragma unroll
        for (int d2 = 0; d2 < 7; ++d2) {
            const v2f xp = *(const v2f*)(xr + 2 * d2);
            const double2 mv = mpack[d2 * 256 + j];
            a += (double)xp.x * mv.x + (double)xp.y * mv.y;
        }
        if (hc) {   // general path: + irs64 * c_j
            double xv[DI]; double sum = 0.0;
            #pragma unroll
            for (int d = 0; d < DI; ++d) { xv[d] = (double)xr[d]; sum += xv[d]; }
            const double mu = sum * (1.0 / (double)DI);
            double vs = 0.0;
            #pragma unroll
            for (int d = 0; d < DI; ++d) { const double t = xv[d] - mu; vs += t * t; }
            const double irs64 = 1.0 / sqrt(vs * (1.0 / (double)DI) + 1e-5);
            a += irs64 * cvec[j];
        }
        const double oa = __shfl_xor(a, 1);
        const int    oj = __shfl_xor(j, 1);
        const int jwin = (a > oa || (a == oa && j < oj)) ? j : oj;
        if ((lane & 1) == 0) jstarS[w][bi][row] = jwin;
    }
    __builtin_amdgcn_wave_barrier();

    // ---- head: z fp64 (28 lanes = 4 bi x 7 classes), softmax fp32 ----
    if (lane < 4 * NC) {
        const int bi = lane / NC, c = lane % NC;
        double zv = zbs[c];
        #pragma unroll
        for (int s = 0; s < SS; ++s)
            zv += (double)wbs[s] * (double)Ts[jstarS[w][bi][s] * NC + c];
        zrowd[w][bi][c] = zv;
    }
    __builtin_amdgcn_wave_barrier();
    if (lane < 4 * NC) {
        const int bi = lane / NC;
        double m = zrowd[w][bi][0];
        #pragma unroll
        for (int c2 = 1; c2 < NC; ++c2) m = fmax(m, zrowd[w][bi][c2]);
        float den = 0.f;
        #pragma unroll
        for (int c2 = 0; c2 < NC; ++c2) den += __expf((float)(zrowd[w][bi][c2] - m));
        const float num = __expf((float)(zrowd[w][bi][lane % NC] - m));
        out[(size_t)gw * 28 + lane] = num / den;
    }
}

extern "C" void kernel_launch(void* const* d_in, const int* in_sizes, int n_in,
                              void* d_out, int out_size, void* d_ws, size_t ws_size,
                              hipStream_t stream) {
    const float* x      = (const float*)d_in[0];
    const float* lookup = (const float*)d_in[1];
    const float* g_st   = (const float*)d_in[2];
    const float* b_st   = (const float*)d_in[3];
    const float* g_sp   = (const float*)d_in[4];
    const float* b_sp   = (const float*)d_in[5];
    const float* g_pp   = (const float*)d_in[6];
    const float* b_pp   = (const float*)d_in[7];
    const float* Wv     = (const float*)d_in[8];
    const float* Wo     = (const float*)d_in[9];
    const float* Wm     = (const float*)d_in[10];
    const float* bm     = (const float*)d_in[11];
    const float* Wb     = (const float*)d_in[12];
    const float* bb     = (const float*)d_in[13];

    double2* mpack = (double2*)((char*)d_ws + WS_MPACK_OFF);
    float*   Tf    = (float*)((char*)d_ws + WS_TF_OFF);
    double*  zbp   = (double*)((char*)d_ws + WS_ZB_OFF);
    double*  cvec  = (double*)((char*)d_ws + WS_CV_OFF);
    int*     hc    = (int*)((char*)d_ws + WS_HC_OFF);

    precompute_kernel<<<1, 256, 0, stream>>>(lookup, g_st, b_st, g_pp, b_pp,
                                             g_sp, b_sp,
                                             Wv, Wo, Wm, bm, Wb, bb,
                                             mpack, Tf, zbp, cvec, hc);
    hopfield_kernel<<<NBLK, 256, 0, stream>>>(x, mpack, cvec, hc, Tf, zbp, Wb,
                                              (float*)d_out);
}